// Round 10
// baseline (450.610 us; speedup 1.0000x reference)
//
#include <hip/hip_runtime.h>
#include <math.h>

#define NA 16384
#define ER 524288
#define EB 32768
#define ET 557056
#define INV_NORM 0.17149858514250882f   // 1/sqrt((ER+EB)/NA) = 1/sqrt(34)
#define SQRT3 1.7320508075688772f
#define RB_STEP (1.5f/9.0f)
#define BINS 512
#define DMAX 2.5f
#define INV_H ((float)BINS / DMAX)
#define T0U (2 * BINS * 128)    // agg0 table: [2][BINS][64][2] uints
#define TLU (2 * BINS * 256)    // layer table: [2][BINS][64][4] uints

typedef unsigned int uint32;
typedef unsigned short ushort16;

__device__ __forceinline__ float sigmoidf_(float x) { return 1.f / (1.f + __expf(-x)); }

__device__ __forceinline__ ushort16 f2bf(float x) {
  uint32 u = __float_as_uint(x);
  u = u + 0x7FFFu + ((u >> 16) & 1u);
  return (ushort16)(u >> 16);
}
__device__ __forceinline__ uint32 packbf(float hi, float lo) {
  return ((uint32)f2bf(hi) << 16) | (uint32)f2bf(lo);
}
__device__ __forceinline__ float bfhi(uint32 u) { return __uint_as_float(u & 0xFFFF0000u); }
__device__ __forceinline__ float bflo(uint32 u) { return __uint_as_float(u << 16); }

// ---------------- CSR build ----------------
__global__ void k_hist(const int* __restrict__ rad, const int* __restrict__ bon, int* __restrict__ count) {
  int e = blockIdx.x * 256 + threadIdx.x;
  int d = (e < ER) ? rad[ER + e] : bon[EB + (e - ER)];
  atomicAdd(&count[d], 1);
}

// single-block fused scan over NA=16384 counts + LPT (degree-descending) node order
__global__ __launch_bounds__(1024) void k_scan_all(const int* __restrict__ count,
                                                   int* __restrict__ offsets,
                                                   int* __restrict__ cursor,
                                                   int* __restrict__ order) {
  __shared__ int ts[1024];
  __shared__ int hist[256];
  __shared__ int hcur[256];
  int t = threadIdx.x;
  if (t < 256) hist[t] = 0;
  int base = t * 16;
  int loc[16], cnts[16];
  int sum = 0;
#pragma unroll
  for (int i = 0; i < 16; ++i) { cnts[i] = count[base + i]; loc[i] = sum; sum += cnts[i]; }
  ts[t] = sum;
  __syncthreads();  // hist zeroed + ts ready
#pragma unroll
  for (int i = 0; i < 16; ++i) atomicAdd(&hist[cnts[i] < 255 ? cnts[i] : 255], 1);
  for (int off = 1; off < 1024; off <<= 1) {
    int x = (t >= off) ? ts[t - off] : 0;
    __syncthreads();
    ts[t] += x;
    __syncthreads();
  }
  int excl = ts[t] - sum;
#pragma unroll
  for (int i = 0; i < 16; ++i) {
    int v = excl + loc[i];
    offsets[base + i] = v;
    cursor[base + i] = v;
  }
  if (t == 1023) offsets[NA] = excl + sum;
  __syncthreads();  // hist atomics done (and scan barriers passed)
  if (t == 0) {     // suffix-sum: bucket d starts after all higher-degree buckets
    int run = 0;
    for (int d = 255; d >= 0; --d) { hcur[d] = run; run += hist[d]; }
  }
  __syncthreads();
#pragma unroll
  for (int i = 0; i < 16; ++i) {
    int d = cnts[i] < 255 ? cnts[i] : 255;
    int p = atomicAdd(&hcur[d], 1);
    order[p] = base + i;
  }
}

// ---------------- fused fill + per-edge record precompute ----------------
// record[slot] (32B): {src, Y0, Y1, Y2, frac, qoffL(uint elems, layer scale), pad, pad}
// agg0 table offset = qoffL >> 1
__global__ void k_fill_pre(const int* __restrict__ rad, const int* __restrict__ bon,
                           int* __restrict__ cursor, const float* __restrict__ pos,
                           float* __restrict__ rec8) {
  int e = blockIdx.x * 256 + threadIdx.x;
  int src, dst, v;
  if (e < ER) { src = rad[e]; dst = rad[ER + e]; v = 0; }
  else        { src = bon[e - ER]; dst = bon[EB + e - ER]; v = 1; }
  float dx = pos[src * 3] - pos[dst * 3];
  float dy = pos[src * 3 + 1] - pos[dst * 3 + 1];
  float dz = pos[src * 3 + 2] - pos[dst * 3 + 2];
  float dist = sqrtf(dx * dx + dy * dy + dz * dz + 1e-12f);
  float inv = 1.f / dist;
  float fq = fminf(dist * INV_H, BINS - 1.001f);
  int q = (int)fq;
  float frac = fq - (float)q;
  int qoffL = (v * BINS + q) << 8;   // 256 uints per layer row
  int slot = atomicAdd(&cursor[dst], 1);
  float* rp = rec8 + (size_t)slot * 8;
  *(float4*)rp = make_float4(__int_as_float(src), SQRT3 * dx * inv, SQRT3 * dy * inv, SQRT3 * dz * inv);
  rp[4] = frac;
  rp[5] = __int_as_float(qoffL);
}

// ---------------- merged embedding + bf16 table build ----------------
// blocks 0..4095: embedding (f32 + bf16 mirror)
// blocks 4096..4863: table build, 4 original 64-thread groups per 256-thread block
__global__ void k_embed_build(const float* __restrict__ atom_tab, const int* __restrict__ types,
                              const float* __restrict__ ns0_w, const float* __restrict__ cnoise,
                              float* __restrict__ s_feat, ushort16* __restrict__ s_bf,
                              const float* __restrict__ We0, const float* __restrict__ We1,
                              const float* __restrict__ We_ss, const float* __restrict__ We_vs,
                              const float* __restrict__ We_sv, const float* __restrict__ We_vv,
                              const float* __restrict__ We_vx, const float* __restrict__ bond_tab,
                              uint32* __restrict__ T0, uint32* __restrict__ TL) {
  int bid = blockIdx.x;
  if (bid < 4096) {
    int tid = bid * 256 + threadIdx.x;
    int c = tid & 63;
    float cn = cnoise[0];
    float v = atom_tab[types[tid >> 6] * 64 + c] * (1.f + cn * ns0_w[c]);
    s_feat[tid] = v;
    s_bf[tid] = f2bf(v);
    return;
  }
  int orig = (bid - 4096) * 4 + (threadIdx.x >> 6);  // 0..3071
  int c = threadIdx.x & 63;
  int q = orig & 511;
  int m = orig >> 9;     // 0..5
  int t = m % 3;
  int v = m / 3;
  float d0 = q * (DMAX / BINS), d1 = (q + 1) * (DMAX / BINS);
  float rb0[8], rb1[8];
#pragma unroll
  for (int k = 0; k < 8; ++k) {
    float f0 = (d0 - (k + 1) * RB_STEP) * (1.f / RB_STEP);
    float f1 = (d1 - (k + 1) * RB_STEP) * (1.f / RB_STEP);
    rb0[k] = 1.12f * __expf(-f0 * f0);
    rb1[k] = 1.12f * __expf(-f1 * f1);
  }
  if (t == 0) {
    float ba = 0, bb = 0, a0 = 0, a1 = 0, b0 = 0, b1 = 0;
#pragma unroll
    for (int k = 0; k < 8; ++k) {
      float bt = bond_tab[v * 8 + k];
      float av_lo = We0[k * 64 + c], av_hi = We0[(8 + k) * 64 + c];
      float bv_lo = We1[k * 64 + c], bv_hi = We1[(8 + k) * 64 + c];
      ba += bt * av_lo; bb += bt * bv_lo;
      a0 += rb0[k] * av_hi; a1 += rb1[k] * av_hi;
      b0 += rb0[k] * bv_hi; b1 += rb1[k] * bv_hi;
    }
    uint32* o = T0 + (((size_t)v * BINS + q) << 7) + c * 2;
    o[0] = packbf(ba + a0, a1 - a0);
    o[1] = packbf(bb + b0, b1 - b0);
  } else {
    int l = t - 1;
    const float* Wss = We_ss + l * 1024;
    const float* Wsv = We_sv + l * 1024;
    const float* WA = (c < 32) ? (We_vs + l * 512) : (We_vx + l * 512);
    const float* WB = (c < 32) ? (We_vv + l * 512) : nullptr;
    int cu = c & 31;
    float sa = 0, sb = 0, s0 = 0, s1 = 0, t0 = 0, t1 = 0;
    float ua = 0, ub = 0, u0 = 0, u1 = 0, w0 = 0, w1 = 0;
#pragma unroll
    for (int k = 0; k < 8; ++k) {
      float bt = bond_tab[v * 8 + k];
      float ss_lo = Wss[k * 64 + c], ss_hi = Wss[(8 + k) * 64 + c];
      float sv_lo = Wsv[k * 64 + c], sv_hi = Wsv[(8 + k) * 64 + c];
      sa += bt * ss_lo; sb += bt * sv_lo;
      s0 += rb0[k] * ss_hi; s1 += rb1[k] * ss_hi;
      t0 += rb0[k] * sv_hi; t1 += rb1[k] * sv_hi;
      float a_lo = WA[k * 32 + cu], a_hi = WA[(8 + k) * 32 + cu];
      ua += bt * a_lo;
      u0 += rb0[k] * a_hi; u1 += rb1[k] * a_hi;
      if (WB) {
        float b_lo = WB[k * 32 + cu], b_hi = WB[(8 + k) * 32 + cu];
        ub += bt * b_lo;
        w0 += rb0[k] * b_hi; w1 += rb1[k] * b_hi;
      }
    }
    uint32* o = TL + (size_t)l * TLU + (((size_t)v * BINS + q) << 8) + c * 4;
    o[0] = packbf(sa + s0, s1 - s0);
    o[1] = packbf(sb + t0, t1 - t0);
    o[2] = packbf(ua + u0, u1 - u0);
    o[3] = WB ? packbf(ub + w0, w1 - w0) : 0u;
  }
}

// ---------------- initial aggregation (R6 body; 128-thread blocks = 2 nodes) ----------------
#define AISSUE(S, eidx) { \
    const float* rp_ = rec8 + (size_t)(eidx) * 8; \
    float4 ra_ = *(const float4*)rp_; float2 rb_ = *(const float2*)(rp_ + 4); \
    S##_f = rb_.x; S##_y0 = ra_.y; S##_y1 = ra_.z; S##_y2 = ra_.w; \
    S##_t = *(const uint2*)(T0c + ((((unsigned)__float_as_int(rb_.y)) << 1) + laneT)); \
    S##_s = *(const ushort16*)(SBc + ((((unsigned)__float_as_int(ra_.x)) << 7) + laneS)); \
  }
#define ACOMP(S) { \
    float w0_ = fmaf(S##_f, bflo(S##_t.x), bfhi(S##_t.x)); \
    float w1_ = fmaf(S##_f, bflo(S##_t.y), bfhi(S##_t.y)); \
    float sv_ = __uint_as_float((uint32)S##_s << 16); \
    acc += w0_ * sv_; \
    float t_ = w1_ * sv_; \
    a0 += t_ * S##_y0; a1 += t_ * S##_y1; a2 += t_ * S##_y2; \
  }

__global__ __launch_bounds__(128, 8) void k_agg0(
    const int* __restrict__ offsets, const int* __restrict__ order,
    const float* __restrict__ rec8,
    const uint32* __restrict__ T0, const ushort16* __restrict__ s_bf,
    float* __restrict__ a_s, float* __restrict__ a_v) {
  int lane = threadIdx.x & 63;
  int n = __builtin_amdgcn_readfirstlane(order[blockIdx.x * 2 + (threadIdx.x >> 6)]);
  const char* T0c = (const char*)T0;
  const char* SBc = (const char*)s_bf;
  unsigned laneT = (unsigned)lane * 8u;   // uint2 per lane
  unsigned laneS = (unsigned)lane * 2u;   // ushort per lane
  float acc = 0, a0 = 0, a1 = 0, a2 = 0;
  int beg = __builtin_amdgcn_readfirstlane(offsets[n]);
  int end = __builtin_amdgcn_readfirstlane(offsets[n + 1]);
  float S0_f, S0_y0, S0_y1, S0_y2; uint2 S0_t; ushort16 S0_s;
  float S1_f, S1_y0, S1_y1, S1_y2; uint2 S1_t; ushort16 S1_s;
  float S2_f, S2_y0, S2_y1, S2_y2; uint2 S2_t; ushort16 S2_s;
  if (beg < end) {
    int last = end - 1;
    AISSUE(S0, beg);
    AISSUE(S1, (beg + 1 < end) ? beg + 1 : last);
    AISSUE(S2, (beg + 2 < end) ? beg + 2 : last);
    int i = beg;
    while (i + 3 <= end) {
      ACOMP(S0); AISSUE(S0, (i + 3 < end) ? i + 3 : last);
      ACOMP(S1); AISSUE(S1, (i + 4 < end) ? i + 4 : last);
      ACOMP(S2); AISSUE(S2, (i + 5 < end) ? i + 5 : last);
      i += 3;
    }
    int rem = end - i;
    if (rem >= 1) ACOMP(S0);
    if (rem >= 2) ACOMP(S1);
  }
  a_s[n * 64 + lane] = acc * INV_NORM;
  *(float4*)(a_v + ((size_t)n << 8) + (lane << 2)) =
      make_float4(a0 * INV_NORM, a1 * INV_NORM, a2 * INV_NORM, 0.f);
}

// ---------------- layer aggregation: full variant (R6 body; 128-thread blocks) ----------------
#define LISSUE(S, eidx) { \
    const float* rp_ = rec8 + (size_t)(eidx) * 8; \
    float4 ra_ = *(const float4*)rp_; float2 rb_ = *(const float2*)(rp_ + 4); \
    S##_f = rb_.x; S##_y0 = ra_.y; S##_y1 = ra_.z; S##_y2 = ra_.w; \
    S##_t = *(const uint4*)(TLc + ((((unsigned)__float_as_int(rb_.y)) << 2) + laneT)); \
    unsigned sb_ = (unsigned)__float_as_int(ra_.x); \
    S##_s = *(const ushort16*)(SHc + ((sb_ << 7) + laneS)); \
    S##_v = *(const uint2*)(VHc + ((sb_ << 8) + laneV)); \
  }
#define LCOMP(S) { \
    float wS_  = fmaf(S##_f, bflo(S##_t.x), bfhi(S##_t.x)); \
    float wSV_ = fmaf(S##_f, bflo(S##_t.y), bfhi(S##_t.y)); \
    float wA_  = fmaf(S##_f, bflo(S##_t.z), bfhi(S##_t.z)); \
    float wB_  = fmaf(S##_f, bflo(S##_t.w), bfhi(S##_t.w)); \
    float ss_ = __uint_as_float((uint32)S##_s << 16); \
    float vx_ = bfhi(S##_v.x), vy_ = bflo(S##_v.x), vz_ = bfhi(S##_v.y); \
    ms += wS_ * ss_; \
    float t_ = wSV_ * ss_; \
    av0 += t_ * S##_y0; av1 += t_ * S##_y1; av2 += t_ * S##_y2; \
    float vdot_ = vx_ * S##_y0 + vy_ * S##_y1 + vz_ * S##_y2; \
    ms2 += wA_ * vdot_; \
    float cx_ = vy_ * S##_y2 - vz_ * S##_y1; \
    float cy_ = vz_ * S##_y0 - vx_ * S##_y2; \
    float cz_ = vx_ * S##_y1 - vy_ * S##_y0; \
    float wM_ = low ? wB_ : wA_; \
    b0 += wM_ * (low ? vx_ : cx_); \
    b1 += wM_ * (low ? vy_ : cy_); \
    b2 += wM_ * (low ? vz_ : cz_); \
  }

__global__ __launch_bounds__(128, 8) void k_agg_layer(
    const float* __restrict__ cnoise, const float* __restrict__ nsw,
    const int* __restrict__ offsets, const int* __restrict__ order,
    const float* __restrict__ rec8,
    const uint32* __restrict__ TL, const ushort16* __restrict__ sh_bf,
    const uint32* __restrict__ vh_bf,
    float* __restrict__ a_s, float* __restrict__ a_v) {
  int lane = threadIdx.x & 63;
  int n = __builtin_amdgcn_readfirstlane(order[blockIdx.x * 2 + (threadIdx.x >> 6)]);
  int vc = lane & 31;
  bool low = lane < 32;
  const char* TLc = (const char*)TL;
  const char* SHc = (const char*)sh_bf;
  const char* VHc = (const char*)vh_bf;
  unsigned laneT = (unsigned)lane * 16u;  // uint4 per lane
  unsigned laneS = (unsigned)lane * 2u;   // ushort per lane
  unsigned laneV = (unsigned)vc * 8u;     // uint2 per lane (dup across halves)
  float cn = cnoise[0];
  float scale_s = 1.f + cn * nsw[lane];
  float scale_v = 1.f + cn * nsw[64 + vc];
  float ms = 0, av0 = 0, av1 = 0, av2 = 0, ms2 = 0, b0 = 0, b1 = 0, b2 = 0;
  int beg = __builtin_amdgcn_readfirstlane(offsets[n]);
  int end = __builtin_amdgcn_readfirstlane(offsets[n + 1]);
  float S0_f, S0_y0, S0_y1, S0_y2; uint4 S0_t; ushort16 S0_s; uint2 S0_v;
  float S1_f, S1_y0, S1_y1, S1_y2; uint4 S1_t; ushort16 S1_s; uint2 S1_v;
  float S2_f, S2_y0, S2_y1, S2_y2; uint4 S2_t; ushort16 S2_s; uint2 S2_v;
  if (beg < end) {
    int last = end - 1;
    LISSUE(S0, beg);
    LISSUE(S1, (beg + 1 < end) ? beg + 1 : last);
    LISSUE(S2, (beg + 2 < end) ? beg + 2 : last);
    int i = beg;
    while (i + 3 <= end) {
      LCOMP(S0); LISSUE(S0, (i + 3 < end) ? i + 3 : last);
      LCOMP(S1); LISSUE(S1, (i + 4 < end) ? i + 4 : last);
      LCOMP(S2); LISSUE(S2, (i + 5 < end) ? i + 5 : last);
      i += 3;
    }
    int rem = end - i;
    if (rem >= 1) LCOMP(S0);
    if (rem >= 2) LCOMP(S1);
  }
  float fs = scale_s * INV_NORM;
  float fv = scale_v * INV_NORM;
  a_s[n * 96 + lane] = ms * fs;
  float* avn = a_v + ((size_t)n << 9);
  *(float4*)(avn + (lane << 2)) = make_float4(av0 * fs, av1 * fs, av2 * fs, 0.f);
  if (low) {
    a_s[n * 96 + 64 + vc] = ms2 * fv;
    *(float4*)(avn + ((64 + vc) << 2)) = make_float4(b0 * fv, b1 * fv, b2 * fv, 0.f);
  } else {
    *(float4*)(avn + ((96 + vc) << 2)) = make_float4(b0 * fv, b1 * fv, b2 * fv, 0.f);
  }
}

// ---------------- layer aggregation: no-s variant (R6 body; 128-thread blocks) ----------------
// NOTE: keeps wA_ (t.z) live so the uint4 table load stays a single dwordx3/x4 —
// R8 showed that a non-contiguous live set {y,w} splits into two dword gathers (−40 µs).
#define LCOMP_NS(S) { \
    float wSV_ = fmaf(S##_f, bflo(S##_t.y), bfhi(S##_t.y)); \
    float wA_  = fmaf(S##_f, bflo(S##_t.z), bfhi(S##_t.z)); \
    float wB_  = fmaf(S##_f, bflo(S##_t.w), bfhi(S##_t.w)); \
    float ss_ = __uint_as_float((uint32)S##_s << 16); \
    float vx_ = bfhi(S##_v.x), vy_ = bflo(S##_v.x), vz_ = bfhi(S##_v.y); \
    float t_ = wSV_ * ss_; \
    av0 += t_ * S##_y0; av1 += t_ * S##_y1; av2 += t_ * S##_y2; \
    float cx_ = vy_ * S##_y2 - vz_ * S##_y1; \
    float cy_ = vz_ * S##_y0 - vx_ * S##_y2; \
    float cz_ = vx_ * S##_y1 - vy_ * S##_y0; \
    float wM_ = low ? wB_ : wA_; \
    b0 += wM_ * (low ? vx_ : cx_); \
    b1 += wM_ * (low ? vy_ : cy_); \
    b2 += wM_ * (low ? vz_ : cz_); \
  }

__global__ __launch_bounds__(128, 8) void k_agg_layer_ns(
    const float* __restrict__ cnoise, const float* __restrict__ nsw,
    const int* __restrict__ offsets, const int* __restrict__ order,
    const float* __restrict__ rec8,
    const uint32* __restrict__ TL, const ushort16* __restrict__ sh_bf,
    const uint32* __restrict__ vh_bf,
    float* __restrict__ a_v) {
  int lane = threadIdx.x & 63;
  int n = __builtin_amdgcn_readfirstlane(order[blockIdx.x * 2 + (threadIdx.x >> 6)]);
  int vc = lane & 31;
  bool low = lane < 32;
  const char* TLc = (const char*)TL;
  const char* SHc = (const char*)sh_bf;
  const char* VHc = (const char*)vh_bf;
  unsigned laneT = (unsigned)lane * 16u;
  unsigned laneS = (unsigned)lane * 2u;
  unsigned laneV = (unsigned)vc * 8u;
  float cn = cnoise[0];
  float scale_s = 1.f + cn * nsw[lane];
  float scale_v = 1.f + cn * nsw[64 + vc];
  float av0 = 0, av1 = 0, av2 = 0, b0 = 0, b1 = 0, b2 = 0;
  int beg = __builtin_amdgcn_readfirstlane(offsets[n]);
  int end = __builtin_amdgcn_readfirstlane(offsets[n + 1]);
  float S0_f, S0_y0, S0_y1, S0_y2; uint4 S0_t; ushort16 S0_s; uint2 S0_v;
  float S1_f, S1_y0, S1_y1, S1_y2; uint4 S1_t; ushort16 S1_s; uint2 S1_v;
  float S2_f, S2_y0, S2_y1, S2_y2; uint4 S2_t; ushort16 S2_s; uint2 S2_v;
  if (beg < end) {
    int last = end - 1;
    LISSUE(S0, beg);
    LISSUE(S1, (beg + 1 < end) ? beg + 1 : last);
    LISSUE(S2, (beg + 2 < end) ? beg + 2 : last);
    int i = beg;
    while (i + 3 <= end) {
      LCOMP_NS(S0); LISSUE(S0, (i + 3 < end) ? i + 3 : last);
      LCOMP_NS(S1); LISSUE(S1, (i + 4 < end) ? i + 4 : last);
      LCOMP_NS(S2); LISSUE(S2, (i + 5 < end) ? i + 5 : last);
      i += 3;
    }
    int rem = end - i;
    if (rem >= 1) LCOMP_NS(S0);
    if (rem >= 2) LCOMP_NS(S1);
  }
  float fs = scale_s * INV_NORM;
  float fv = scale_v * INV_NORM;
  float* avn = a_v + ((size_t)n << 9);
  *(float4*)(avn + (lane << 2)) = make_float4(av0 * fs, av1 * fs, av2 * fs, 0.f);
  if (low) {
    *(float4*)(avn + ((64 + vc) << 2)) = make_float4(b0 * fv, b1 * fv, b2 * fv, 0.f);
  } else {
    *(float4*)(avn + ((96 + vc) << 2)) = make_float4(b0 * fv, b1 * fv, b2 * fv, 0.f);
  }
}

// ---------------- merged init projections ----------------
// blocks 0..2047: s-path (36KB LDS); blocks 2048..4095: v-path (8KB of the same buffer)
__global__ __launch_bounds__(256, 4) void k_init(
    const float* __restrict__ a_s, const float* __restrict__ s_feat,
    const float* __restrict__ Ws0, const float* __restrict__ Wself0,
    const float* __restrict__ a_v, const float* __restrict__ Wv0,
    float* __restrict__ sh, ushort16* __restrict__ sh_bf,
    float* __restrict__ vh, uint32* __restrict__ vh_bf) {
  __shared__ __align__(16) char ldsbuf[36864];
  int tid = threadIdx.x;
  int bid = blockIdx.x;
  if (bid < 2048) {
    float* W1 = (float*)ldsbuf;              // 16KB
    float* W2 = (float*)(ldsbuf + 16384);    // 16KB
    float* La = (float*)(ldsbuf + 32768);    // 2KB
    float* Lf = (float*)(ldsbuf + 34816);    // 2KB
    for (int i = tid; i < 1024; i += 256) {
      ((float4*)W1)[i] = ((const float4*)Ws0)[i];
      ((float4*)W2)[i] = ((const float4*)Wself0)[i];
    }
    int base = bid * 8;
    for (int i = tid; i < 512; i += 256) {
      La[i] = a_s[(size_t)base * 64 + i];
      Lf[i] = s_feat[(size_t)base * 64 + i];
    }
    __syncthreads();
    int d = tid & 63, g = tid >> 6;
    int n0 = base + g * 2;
    const float* A0 = La + g * 128;
    const float* A1 = A0 + 64;
    const float* F0 = Lf + g * 128;
    const float* F1 = F0 + 64;
    float a0 = 0, a1 = 0;
#pragma unroll 8
    for (int c = 0; c < 64; ++c) {
      float w1 = W1[c * 64 + d], w2 = W2[c * 64 + d];
      a0 += A0[c] * w1 + F0[c] * w2;
      a1 += A1[c] * w1 + F1[c] * w2;
    }
    sh[(size_t)n0 * 64 + d] = a0;
    sh[(size_t)(n0 + 1) * 64 + d] = a1;
    sh_bf[(size_t)n0 * 64 + d] = f2bf(a0);
    sh_bf[(size_t)(n0 + 1) * 64 + d] = f2bf(a1);
  } else {
    float* W = (float*)ldsbuf;  // 8KB
    for (int i = tid; i < 512; i += 256) ((float4*)W)[i] = ((const float4*)Wv0)[i];
    __syncthreads();
    int d = tid & 31, g = tid >> 5;
    int n = (bid - 2048) * 8 + g;
    const float4* av = (const float4*)(a_v + ((size_t)n << 8));
    float x = 0, y = 0, z = 0;
#pragma unroll 4
    for (int c = 0; c < 64; ++c) {
      float4 a = av[c];
      float w = W[c * 32 + d];
      x += a.x * w; y += a.y * w; z += a.z * w;
    }
    *(float4*)(vh + ((size_t)n << 7) + (d << 2)) = make_float4(x, y, z, 0.f);
    *(uint2*)(vh_bf + ((size_t)n << 6) + (d << 1)) = make_uint2(packbf(x, y), packbf(z, 0.f));
  }
}

// ---------------- mix/self/skip: LDS-staged matvecs (+ bf16 mirrors) ----------------
__global__ __launch_bounds__(256, 4) void k_mix_s(
    const float* __restrict__ a_s, const float* __restrict__ sh_in,
    const float* __restrict__ Wmix_s, const float* __restrict__ Wself_s,
    const float* __restrict__ nsw, const float* __restrict__ skw,
    const float* __restrict__ skb, const float* __restrict__ cnoise,
    float* __restrict__ sh_out, ushort16* __restrict__ sh_bf_out) {
  __shared__ float Wm[96 * 64];   // 24KB
  __shared__ float Wsf[64 * 64];  // 16KB (scale folded in)
  __shared__ float La[8 * 96];    // 3KB
  int tid = threadIdx.x;
  float cn = cnoise[0];
  for (int i = tid; i < 96 * 16; i += 256) ((float4*)Wm)[i] = ((const float4*)Wmix_s)[i];
  for (int i = tid; i < 64 * 16; i += 256) {
    float4 wv = ((const float4*)Wself_s)[i];
    int c = i >> 4;
    float sc = 1.f + cn * nsw[c];
    wv.x *= sc; wv.y *= sc; wv.z *= sc; wv.w *= sc;
    ((float4*)Wsf)[i] = wv;
  }
  int base = blockIdx.x * 8;
  for (int i = tid; i < 8 * 96; i += 256) La[i] = a_s[(size_t)base * 96 + i];
  __syncthreads();
  int d = tid & 63, g = tid >> 6;
  int n0 = base + g * 2;
  const float* A0 = La + (g * 2) * 96;
  const float* A1 = A0 + 96;
  const float* s0p = sh_in + (size_t)n0 * 64;
  const float* s1p = s0p + 64;
  float acc0 = 0, acc1 = 0;
#pragma unroll 8
  for (int c = 0; c < 96; ++c) {
    float w = Wm[c * 64 + d];
    acc0 += A0[c] * w;
    acc1 += A1[c] * w;
  }
#pragma unroll 8
  for (int c = 0; c < 64; ++c) {
    float w = Wsf[c * 64 + d];
    acc0 += s0p[c] * w;
    acc1 += s1p[c] * w;
  }
  float g1 = sigmoidf_(skb[d] + cn * skw[d]);
  float g2 = sigmoidf_(skb[64 + d] + cn * skw[64 + d]);
  float o0 = g1 * s0p[d] + g2 * acc0;
  float o1 = g1 * s1p[d] + g2 * acc1;
  sh_out[(size_t)n0 * 64 + d] = o0;
  sh_out[(size_t)(n0 + 1) * 64 + d] = o1;
  sh_bf_out[(size_t)n0 * 64 + d] = f2bf(o0);
  sh_bf_out[(size_t)(n0 + 1) * 64 + d] = f2bf(o1);
}

// last==0: write vh_out + bf16 mirror. last==1: fused final projection to out, no stores.
__global__ __launch_bounds__(256, 4) void k_mix_v(
    const float* __restrict__ a_v, const float* __restrict__ vh_in,
    const float* __restrict__ Wmix_v, const float* __restrict__ Wself_v,
    const float* __restrict__ nsw, const float* __restrict__ skw,
    const float* __restrict__ skb, const float* __restrict__ cnoise,
    float* __restrict__ vh_out, uint32* __restrict__ vh_bf_out,
    const float* __restrict__ w_out, const float* __restrict__ gain,
    float* __restrict__ out, int last) {
  __shared__ float Wm[128 * 32];   // 16KB
  __shared__ float Wsf[32 * 32];   // 4KB (scale folded in)
  int tid = threadIdx.x;
  float cn = cnoise[0];
  for (int i = tid; i < 128 * 8; i += 256) ((float4*)Wm)[i] = ((const float4*)Wmix_v)[i];
  for (int i = tid; i < 32 * 8; i += 256) {
    float4 wv = ((const float4*)Wself_v)[i];
    int c = i >> 3;
    float sc = 1.f + cn * nsw[64 + c];
    wv.x *= sc; wv.y *= sc; wv.z *= sc; wv.w *= sc;
    ((float4*)Wsf)[i] = wv;
  }
  __syncthreads();
  int d = tid & 31, g = tid >> 5;
  int n = blockIdx.x * 8 + g;
  const float4* av = (const float4*)(a_v + ((size_t)n << 9));
  const float4* vr = (const float4*)(vh_in + ((size_t)n << 7));
  float x = 0, y = 0, z = 0;
#pragma unroll 4
  for (int c = 0; c < 128; ++c) {
    float4 a = av[c];
    float w = Wm[c * 32 + d];
    x += a.x * w; y += a.y * w; z += a.z * w;
  }
#pragma unroll 4
  for (int c = 0; c < 32; ++c) {
    float4 vv = vr[c];
    float w = Wsf[c * 32 + d];
    x += vv.x * w; y += vv.y * w; z += vv.z * w;
  }
  float g3 = sigmoidf_(skb[128 + d] + cn * skw[128 + d]);
  float g4 = sigmoidf_(skb[160 + d] + cn * skw[160 + d]);
  float4 vi = vr[d];
  float ox = g3 * vi.x + g4 * x;
  float oy = g3 * vi.y + g4 * y;
  float oz = g3 * vi.z + g4 * z;
  if (!last) {
    *(float4*)(vh_out + ((size_t)n << 7) + (d << 2)) = make_float4(ox, oy, oz, 0.f);
    *(uint2*)(vh_bf_out + ((size_t)n << 6) + (d << 1)) = make_uint2(packbf(ox, oy), packbf(oz, 0.f));
  } else {
    // fused final projection: out[n][i] = gain * sum_c w_out[c] * o_i[c]
    float wo = w_out[d];
    float px = wo * ox, py = wo * oy, pz = wo * oz;
#pragma unroll
    for (int m = 16; m >= 1; m >>= 1) {
      px += __shfl_xor(px, m, 32);
      py += __shfl_xor(py, m, 32);
      pz += __shfl_xor(pz, m, 32);
    }
    if (d == 0) {
      float gg = gain[0];
      out[n * 3 + 0] = px * gg;
      out[n * 3 + 1] = py * gg;
      out[n * 3 + 2] = pz * gg;
    }
  }
}

extern "C" void kernel_launch(void* const* d_in, const int* in_sizes, int n_in,
                              void* d_out, int out_size, void* d_ws, size_t ws_size,
                              hipStream_t stream) {
  (void)in_sizes; (void)n_in; (void)out_size; (void)ws_size;
  const float* pos     = (const float*)d_in[0];
  const float* cn      = (const float*)d_in[1];
  const int*   types   = (const int*)d_in[2];
  const int*   rad     = (const int*)d_in[3];
  const int*   bon     = (const int*)d_in[4];
  const float* atom_tab= (const float*)d_in[5];
  const float* bond_tab= (const float*)d_in[6];
  const float* ns0_w   = (const float*)d_in[7];
  const float* We0     = (const float*)d_in[8];
  const float* We1     = (const float*)d_in[9];
  const float* Wself0  = (const float*)d_in[10];
  const float* Ws0     = (const float*)d_in[11];
  const float* Wv0     = (const float*)d_in[12];
  const float* ns_w    = (const float*)d_in[13];
  const float* We_ss   = (const float*)d_in[14];
  const float* We_vs   = (const float*)d_in[15];
  const float* We_sv   = (const float*)d_in[16];
  const float* We_vv   = (const float*)d_in[17];
  const float* We_vx   = (const float*)d_in[18];
  const float* Wmix_s  = (const float*)d_in[19];
  const float* Wmix_v  = (const float*)d_in[20];
  const float* Wself_s = (const float*)d_in[21];
  const float* Wself_v = (const float*)d_in[22];
  const float* skip_w  = (const float*)d_in[23];
  const float* skip_b  = (const float*)d_in[24];
  const float* w_out   = (const float*)d_in[25];
  const float* gain    = (const float*)d_in[26];

  char* ws = (char*)d_ws;
  size_t o = 0;
  auto alloc = [&](size_t bytes) -> void* {
    void* p = ws + o;
    o += (bytes + 255) & ~(size_t)255;
    return p;
  };
  float* s_feat  = (float*)alloc((size_t)NA * 64 * 4);
  ushort16* s_bf = (ushort16*)alloc((size_t)NA * 64 * 2);
  float* a_s     = (float*)alloc((size_t)NA * 96 * 4);
  float* a_v     = (float*)alloc((size_t)NA * 512 * 4);  // [n][128][4]; agg0 uses [n][64][4]
  float* sh0     = (float*)alloc((size_t)NA * 64 * 4);
  float* sh1     = (float*)alloc((size_t)NA * 64 * 4);
  ushort16* shbf0= (ushort16*)alloc((size_t)NA * 64 * 2);
  ushort16* shbf1= (ushort16*)alloc((size_t)NA * 64 * 2);
  float* vh0     = (float*)alloc((size_t)NA * 128 * 4);  // [n][32][4]
  float* vh1     = (float*)alloc((size_t)NA * 128 * 4);
  uint32* vhbf0  = (uint32*)alloc((size_t)NA * 64 * 4);  // [n][32][2] uints
  uint32* vhbf1  = (uint32*)alloc((size_t)NA * 64 * 4);
  int* count     = (int*)alloc((size_t)NA * 4);
  int* offsets   = (int*)alloc((size_t)(NA + 1) * 4);
  int* cursor    = (int*)alloc((size_t)NA * 4);
  int* order     = (int*)alloc((size_t)NA * 4);
  float* rec8    = (float*)alloc((size_t)ET * 32);
  uint32* T0     = (uint32*)alloc((size_t)T0U * 4);
  uint32* TL     = (uint32*)alloc((size_t)2 * TLU * 4);
  float* shb[2]  = {sh0, sh1};
  ushort16* shbf[2] = {shbf0, shbf1};
  float* vhb[2]  = {vh0, vh1};
  uint32* vhbf[2]= {vhbf0, vhbf1};

  // CSR build + LPT order + tables
  hipMemsetAsync(count, 0, (size_t)NA * 4, stream);
  k_hist<<<ET / 256, 256, 0, stream>>>(rad, bon, count);
  k_scan_all<<<1, 1024, 0, stream>>>(count, offsets, cursor, order);
  k_fill_pre<<<ET / 256, 256, 0, stream>>>(rad, bon, cursor, pos, rec8);
  k_embed_build<<<4096 + 768, 256, 0, stream>>>(atom_tab, types, ns0_w, cn, s_feat, s_bf,
                                                We0, We1, We_ss, We_vs, We_sv, We_vv, We_vx,
                                                bond_tab, T0, TL);

  k_agg0<<<NA / 2, 128, 0, stream>>>(offsets, order, rec8, T0, s_bf, a_s, a_v);
  k_init<<<4096, 256, 0, stream>>>(a_s, s_feat, Ws0, Wself0, a_v, Wv0,
                                   shb[0], shbf[0], vhb[0], vhbf[0]);

  // layer 0 (full)
  k_agg_layer<<<NA / 2, 128, 0, stream>>>(
      cn, ns_w, offsets, order, rec8, TL, shbf[0], vhbf[0], a_s, a_v);
  k_mix_s<<<NA / 8, 256, 0, stream>>>(
      a_s, shb[0], Wmix_s, Wself_s, ns_w, skip_w, skip_b, cn, shb[1], shbf[1]);
  k_mix_v<<<NA / 8, 256, 0, stream>>>(
      a_v, vhb[0], Wmix_v, Wself_v, ns_w, skip_w, skip_b, cn,
      vhb[1], vhbf[1], w_out, gain, (float*)d_out, 0);

  // layer 1 (s-output dead: NS agg, no mix_s, fused final projection)
  k_agg_layer_ns<<<NA / 2, 128, 0, stream>>>(
      cn, ns_w + 96, offsets, order, rec8, TL + (size_t)TLU, shbf[1], vhbf[1], a_v);
  k_mix_v<<<NA / 8, 256, 0, stream>>>(
      a_v, vhb[1], Wmix_v + 128 * 32, Wself_v + 32 * 32,
      ns_w + 96, skip_w + 192, skip_b + 192, cn,
      nullptr, nullptr, w_out, gain, (float*)d_out, 1);
}

// Round 11
// 445.463 us; speedup vs baseline: 1.0116x; 1.0116x over previous
//
#include <hip/hip_runtime.h>
#include <math.h>

#define NA 16384
#define ER 524288
#define EB 32768
#define ET 557056
#define INV_NORM 0.17149858514250882f   // 1/sqrt((ER+EB)/NA) = 1/sqrt(34)
#define SQRT3 1.7320508075688772f
#define RB_STEP (1.5f/9.0f)
#define BINS 512
#define DMAX 2.5f
#define INV_H ((float)BINS / DMAX)
#define T0U (2 * BINS * 128)    // agg0 table: [2][BINS][64][2] uints
#define TLU (2 * BINS * 256)    // layer table: [2][BINS][64][4] uints

typedef unsigned int uint32;
typedef unsigned short ushort16;

__device__ __forceinline__ float sigmoidf_(float x) { return 1.f / (1.f + __expf(-x)); }

__device__ __forceinline__ ushort16 f2bf(float x) {
  uint32 u = __float_as_uint(x);
  u = u + 0x7FFFu + ((u >> 16) & 1u);
  return (ushort16)(u >> 16);
}
__device__ __forceinline__ uint32 packbf(float hi, float lo) {
  return ((uint32)f2bf(hi) << 16) | (uint32)f2bf(lo);
}
__device__ __forceinline__ float bfhi(uint32 u) { return __uint_as_float(u & 0xFFFF0000u); }
__device__ __forceinline__ float bflo(uint32 u) { return __uint_as_float(u << 16); }

// ---------------- CSR build ----------------
__global__ void k_hist(const int* __restrict__ rad, const int* __restrict__ bon, int* __restrict__ count) {
  int e = blockIdx.x * 256 + threadIdx.x;
  int d = (e < ER) ? rad[ER + e] : bon[EB + (e - ER)];
  atomicAdd(&count[d], 1);
}

// single-block fused scan over NA=16384 counts + LPT (degree-descending) node order
__global__ __launch_bounds__(1024) void k_scan_all(const int* __restrict__ count,
                                                   int* __restrict__ offsets,
                                                   int* __restrict__ cursor,
                                                   int* __restrict__ order) {
  __shared__ int ts[1024];
  __shared__ int hist[256];
  __shared__ int hcur[256];
  int t = threadIdx.x;
  if (t < 256) hist[t] = 0;
  int base = t * 16;
  int loc[16], cnts[16];
  int sum = 0;
#pragma unroll
  for (int i = 0; i < 16; ++i) { cnts[i] = count[base + i]; loc[i] = sum; sum += cnts[i]; }
  ts[t] = sum;
  __syncthreads();  // hist zeroed + ts ready
#pragma unroll
  for (int i = 0; i < 16; ++i) atomicAdd(&hist[cnts[i] < 255 ? cnts[i] : 255], 1);
  for (int off = 1; off < 1024; off <<= 1) {
    int x = (t >= off) ? ts[t - off] : 0;
    __syncthreads();
    ts[t] += x;
    __syncthreads();
  }
  int excl = ts[t] - sum;
#pragma unroll
  for (int i = 0; i < 16; ++i) {
    int v = excl + loc[i];
    offsets[base + i] = v;
    cursor[base + i] = v;
  }
  if (t == 1023) offsets[NA] = excl + sum;
  __syncthreads();  // hist atomics done (and scan barriers passed)
  if (t == 0) {     // suffix-sum: bucket d starts after all higher-degree buckets
    int run = 0;
    for (int d = 255; d >= 0; --d) { hcur[d] = run; run += hist[d]; }
  }
  __syncthreads();
#pragma unroll
  for (int i = 0; i < 16; ++i) {
    int d = cnts[i] < 255 ? cnts[i] : 255;
    int p = atomicAdd(&hcur[d], 1);
    order[p] = base + i;
  }
}

// ---------------- fused fill + per-edge record precompute ----------------
// record[slot] (32B): {src, Y0, Y1, Y2, frac, qoffL(uint elems, layer scale), pad, pad}
// agg0 table offset = qoffL >> 1
__global__ void k_fill_pre(const int* __restrict__ rad, const int* __restrict__ bon,
                           int* __restrict__ cursor, const float* __restrict__ pos,
                           float* __restrict__ rec8) {
  int e = blockIdx.x * 256 + threadIdx.x;
  int src, dst, v;
  if (e < ER) { src = rad[e]; dst = rad[ER + e]; v = 0; }
  else        { src = bon[e - ER]; dst = bon[EB + e - ER]; v = 1; }
  float dx = pos[src * 3] - pos[dst * 3];
  float dy = pos[src * 3 + 1] - pos[dst * 3 + 1];
  float dz = pos[src * 3 + 2] - pos[dst * 3 + 2];
  float dist = sqrtf(dx * dx + dy * dy + dz * dz + 1e-12f);
  float inv = 1.f / dist;
  float fq = fminf(dist * INV_H, BINS - 1.001f);
  int q = (int)fq;
  float frac = fq - (float)q;
  int qoffL = (v * BINS + q) << 8;   // 256 uints per layer row
  int slot = atomicAdd(&cursor[dst], 1);
  float* rp = rec8 + (size_t)slot * 8;
  *(float4*)rp = make_float4(__int_as_float(src), SQRT3 * dx * inv, SQRT3 * dy * inv, SQRT3 * dz * inv);
  rp[4] = frac;
  rp[5] = __int_as_float(qoffL);
}

// ---------------- merged embedding + bf16 table build ----------------
// blocks 0..4095: embedding (f32 + bf16 mirror)
// blocks 4096..4863: table build, 4 original 64-thread groups per 256-thread block
__global__ void k_embed_build(const float* __restrict__ atom_tab, const int* __restrict__ types,
                              const float* __restrict__ ns0_w, const float* __restrict__ cnoise,
                              float* __restrict__ s_feat, ushort16* __restrict__ s_bf,
                              const float* __restrict__ We0, const float* __restrict__ We1,
                              const float* __restrict__ We_ss, const float* __restrict__ We_vs,
                              const float* __restrict__ We_sv, const float* __restrict__ We_vv,
                              const float* __restrict__ We_vx, const float* __restrict__ bond_tab,
                              uint32* __restrict__ T0, uint32* __restrict__ TL) {
  int bid = blockIdx.x;
  if (bid < 4096) {
    int tid = bid * 256 + threadIdx.x;
    int c = tid & 63;
    float cn = cnoise[0];
    float v = atom_tab[types[tid >> 6] * 64 + c] * (1.f + cn * ns0_w[c]);
    s_feat[tid] = v;
    s_bf[tid] = f2bf(v);
    return;
  }
  int orig = (bid - 4096) * 4 + (threadIdx.x >> 6);  // 0..3071
  int c = threadIdx.x & 63;
  int q = orig & 511;
  int m = orig >> 9;     // 0..5
  int t = m % 3;
  int v = m / 3;
  float d0 = q * (DMAX / BINS), d1 = (q + 1) * (DMAX / BINS);
  float rb0[8], rb1[8];
#pragma unroll
  for (int k = 0; k < 8; ++k) {
    float f0 = (d0 - (k + 1) * RB_STEP) * (1.f / RB_STEP);
    float f1 = (d1 - (k + 1) * RB_STEP) * (1.f / RB_STEP);
    rb0[k] = 1.12f * __expf(-f0 * f0);
    rb1[k] = 1.12f * __expf(-f1 * f1);
  }
  if (t == 0) {
    float ba = 0, bb = 0, a0 = 0, a1 = 0, b0 = 0, b1 = 0;
#pragma unroll
    for (int k = 0; k < 8; ++k) {
      float bt = bond_tab[v * 8 + k];
      float av_lo = We0[k * 64 + c], av_hi = We0[(8 + k) * 64 + c];
      float bv_lo = We1[k * 64 + c], bv_hi = We1[(8 + k) * 64 + c];
      ba += bt * av_lo; bb += bt * bv_lo;
      a0 += rb0[k] * av_hi; a1 += rb1[k] * av_hi;
      b0 += rb0[k] * bv_hi; b1 += rb1[k] * bv_hi;
    }
    uint32* o = T0 + (((size_t)v * BINS + q) << 7) + c * 2;
    o[0] = packbf(ba + a0, a1 - a0);
    o[1] = packbf(bb + b0, b1 - b0);
  } else {
    int l = t - 1;
    const float* Wss = We_ss + l * 1024;
    const float* Wsv = We_sv + l * 1024;
    const float* WA = (c < 32) ? (We_vs + l * 512) : (We_vx + l * 512);
    const float* WB = (c < 32) ? (We_vv + l * 512) : nullptr;
    int cu = c & 31;
    float sa = 0, sb = 0, s0 = 0, s1 = 0, t0 = 0, t1 = 0;
    float ua = 0, ub = 0, u0 = 0, u1 = 0, w0 = 0, w1 = 0;
#pragma unroll
    for (int k = 0; k < 8; ++k) {
      float bt = bond_tab[v * 8 + k];
      float ss_lo = Wss[k * 64 + c], ss_hi = Wss[(8 + k) * 64 + c];
      float sv_lo = Wsv[k * 64 + c], sv_hi = Wsv[(8 + k) * 64 + c];
      sa += bt * ss_lo; sb += bt * sv_lo;
      s0 += rb0[k] * ss_hi; s1 += rb1[k] * ss_hi;
      t0 += rb0[k] * sv_hi; t1 += rb1[k] * sv_hi;
      float a_lo = WA[k * 32 + cu], a_hi = WA[(8 + k) * 32 + cu];
      ua += bt * a_lo;
      u0 += rb0[k] * a_hi; u1 += rb1[k] * a_hi;
      if (WB) {
        float b_lo = WB[k * 32 + cu], b_hi = WB[(8 + k) * 32 + cu];
        ub += bt * b_lo;
        w0 += rb0[k] * b_hi; w1 += rb1[k] * b_hi;
      }
    }
    uint32* o = TL + (size_t)l * TLU + (((size_t)v * BINS + q) << 8) + c * 4;
    o[0] = packbf(sa + s0, s1 - s0);
    o[1] = packbf(sb + t0, t1 - t0);
    o[2] = packbf(ua + u0, u1 - u0);
    o[3] = WB ? packbf(ub + w0, w1 - w0) : 0u;
  }
}

// ---------------- initial aggregation (verified form: 256 threads, 4 nodes/block) ----------------
#define AISSUE(S, eidx) { \
    const float* rp_ = rec8 + (size_t)(eidx) * 8; \
    float4 ra_ = *(const float4*)rp_; float2 rb_ = *(const float2*)(rp_ + 4); \
    S##_f = rb_.x; S##_y0 = ra_.y; S##_y1 = ra_.z; S##_y2 = ra_.w; \
    S##_t = *(const uint2*)(T0c + ((((unsigned)__float_as_int(rb_.y)) << 1) + laneT)); \
    S##_s = *(const ushort16*)(SBc + ((((unsigned)__float_as_int(ra_.x)) << 7) + laneS)); \
  }
#define ACOMP(S) { \
    float w0_ = fmaf(S##_f, bflo(S##_t.x), bfhi(S##_t.x)); \
    float w1_ = fmaf(S##_f, bflo(S##_t.y), bfhi(S##_t.y)); \
    float sv_ = __uint_as_float((uint32)S##_s << 16); \
    acc += w0_ * sv_; \
    float t_ = w1_ * sv_; \
    a0 += t_ * S##_y0; a1 += t_ * S##_y1; a2 += t_ * S##_y2; \
  }

__global__ __launch_bounds__(256, 8) void k_agg0(
    const int* __restrict__ offsets, const int* __restrict__ order,
    const float* __restrict__ rec8,
    const uint32* __restrict__ T0, const ushort16* __restrict__ s_bf,
    float* __restrict__ a_s, float* __restrict__ a_v) {
  int lane = threadIdx.x & 63;
  int n = __builtin_amdgcn_readfirstlane(order[blockIdx.x * 4 + (threadIdx.x >> 6)]);
  const char* T0c = (const char*)T0;
  const char* SBc = (const char*)s_bf;
  unsigned laneT = (unsigned)lane * 8u;   // uint2 per lane
  unsigned laneS = (unsigned)lane * 2u;   // ushort per lane
  float acc = 0, a0 = 0, a1 = 0, a2 = 0;
  int beg = __builtin_amdgcn_readfirstlane(offsets[n]);
  int end = __builtin_amdgcn_readfirstlane(offsets[n + 1]);
  float S0_f, S0_y0, S0_y1, S0_y2; uint2 S0_t; ushort16 S0_s;
  float S1_f, S1_y0, S1_y1, S1_y2; uint2 S1_t; ushort16 S1_s;
  float S2_f, S2_y0, S2_y1, S2_y2; uint2 S2_t; ushort16 S2_s;
  if (beg < end) {
    int last = end - 1;
    AISSUE(S0, beg);
    AISSUE(S1, (beg + 1 < end) ? beg + 1 : last);
    AISSUE(S2, (beg + 2 < end) ? beg + 2 : last);
    int i = beg;
    while (i + 3 <= end) {
      ACOMP(S0); AISSUE(S0, (i + 3 < end) ? i + 3 : last);
      ACOMP(S1); AISSUE(S1, (i + 4 < end) ? i + 4 : last);
      ACOMP(S2); AISSUE(S2, (i + 5 < end) ? i + 5 : last);
      i += 3;
    }
    int rem = end - i;
    if (rem >= 1) ACOMP(S0);
    if (rem >= 2) ACOMP(S1);
  }
  a_s[n * 64 + lane] = acc * INV_NORM;
  *(float4*)(a_v + ((size_t)n << 8) + (lane << 2)) =
      make_float4(a0 * INV_NORM, a1 * INV_NORM, a2 * INV_NORM, 0.f);
}

// ---------------- layer aggregation: full variant (verified form) ----------------
#define LISSUE(S, eidx) { \
    const float* rp_ = rec8 + (size_t)(eidx) * 8; \
    float4 ra_ = *(const float4*)rp_; float2 rb_ = *(const float2*)(rp_ + 4); \
    S##_f = rb_.x; S##_y0 = ra_.y; S##_y1 = ra_.z; S##_y2 = ra_.w; \
    S##_t = *(const uint4*)(TLc + ((((unsigned)__float_as_int(rb_.y)) << 2) + laneT)); \
    unsigned sb_ = (unsigned)__float_as_int(ra_.x); \
    S##_s = *(const ushort16*)(SHc + ((sb_ << 7) + laneS)); \
    S##_v = *(const uint2*)(VHc + ((sb_ << 8) + laneV)); \
  }
#define LCOMP(S) { \
    float wS_  = fmaf(S##_f, bflo(S##_t.x), bfhi(S##_t.x)); \
    float wSV_ = fmaf(S##_f, bflo(S##_t.y), bfhi(S##_t.y)); \
    float wA_  = fmaf(S##_f, bflo(S##_t.z), bfhi(S##_t.z)); \
    float wB_  = fmaf(S##_f, bflo(S##_t.w), bfhi(S##_t.w)); \
    float ss_ = __uint_as_float((uint32)S##_s << 16); \
    float vx_ = bfhi(S##_v.x), vy_ = bflo(S##_v.x), vz_ = bfhi(S##_v.y); \
    ms += wS_ * ss_; \
    float t_ = wSV_ * ss_; \
    av0 += t_ * S##_y0; av1 += t_ * S##_y1; av2 += t_ * S##_y2; \
    float vdot_ = vx_ * S##_y0 + vy_ * S##_y1 + vz_ * S##_y2; \
    ms2 += wA_ * vdot_; \
    float cx_ = vy_ * S##_y2 - vz_ * S##_y1; \
    float cy_ = vz_ * S##_y0 - vx_ * S##_y2; \
    float cz_ = vx_ * S##_y1 - vy_ * S##_y0; \
    float wM_ = low ? wB_ : wA_; \
    b0 += wM_ * (low ? vx_ : cx_); \
    b1 += wM_ * (low ? vy_ : cy_); \
    b2 += wM_ * (low ? vz_ : cz_); \
  }

__global__ __launch_bounds__(256, 8) void k_agg_layer(
    const float* __restrict__ cnoise, const float* __restrict__ nsw,
    const int* __restrict__ offsets, const int* __restrict__ order,
    const float* __restrict__ rec8,
    const uint32* __restrict__ TL, const ushort16* __restrict__ sh_bf,
    const uint32* __restrict__ vh_bf,
    float* __restrict__ a_s, float* __restrict__ a_v) {
  int lane = threadIdx.x & 63;
  int n = __builtin_amdgcn_readfirstlane(order[blockIdx.x * 4 + (threadIdx.x >> 6)]);
  int vc = lane & 31;
  bool low = lane < 32;
  const char* TLc = (const char*)TL;
  const char* SHc = (const char*)sh_bf;
  const char* VHc = (const char*)vh_bf;
  unsigned laneT = (unsigned)lane * 16u;  // uint4 per lane
  unsigned laneS = (unsigned)lane * 2u;   // ushort per lane
  unsigned laneV = (unsigned)vc * 8u;     // uint2 per lane (dup across halves)
  float cn = cnoise[0];
  float scale_s = 1.f + cn * nsw[lane];
  float scale_v = 1.f + cn * nsw[64 + vc];
  float ms = 0, av0 = 0, av1 = 0, av2 = 0, ms2 = 0, b0 = 0, b1 = 0, b2 = 0;
  int beg = __builtin_amdgcn_readfirstlane(offsets[n]);
  int end = __builtin_amdgcn_readfirstlane(offsets[n + 1]);
  float S0_f, S0_y0, S0_y1, S0_y2; uint4 S0_t; ushort16 S0_s; uint2 S0_v;
  float S1_f, S1_y0, S1_y1, S1_y2; uint4 S1_t; ushort16 S1_s; uint2 S1_v;
  float S2_f, S2_y0, S2_y1, S2_y2; uint4 S2_t; ushort16 S2_s; uint2 S2_v;
  if (beg < end) {
    int last = end - 1;
    LISSUE(S0, beg);
    LISSUE(S1, (beg + 1 < end) ? beg + 1 : last);
    LISSUE(S2, (beg + 2 < end) ? beg + 2 : last);
    int i = beg;
    while (i + 3 <= end) {
      LCOMP(S0); LISSUE(S0, (i + 3 < end) ? i + 3 : last);
      LCOMP(S1); LISSUE(S1, (i + 4 < end) ? i + 4 : last);
      LCOMP(S2); LISSUE(S2, (i + 5 < end) ? i + 5 : last);
      i += 3;
    }
    int rem = end - i;
    if (rem >= 1) LCOMP(S0);
    if (rem >= 2) LCOMP(S1);
  }
  float fs = scale_s * INV_NORM;
  float fv = scale_v * INV_NORM;
  a_s[n * 96 + lane] = ms * fs;
  float* avn = a_v + ((size_t)n << 9);
  *(float4*)(avn + (lane << 2)) = make_float4(av0 * fs, av1 * fs, av2 * fs, 0.f);
  if (low) {
    a_s[n * 96 + 64 + vc] = ms2 * fv;
    *(float4*)(avn + ((64 + vc) << 2)) = make_float4(b0 * fv, b1 * fv, b2 * fv, 0.f);
  } else {
    *(float4*)(avn + ((96 + vc) << 2)) = make_float4(b0 * fv, b1 * fv, b2 * fv, 0.f);
  }
}

// ---------------- layer aggregation: no-s variant (verified form) ----------------
// NOTE: keeps wA_ (t.z) live so the uint4 table load stays a single dwordx3/x4 —
// R8 showed that a non-contiguous live set {y,w} splits into two dword gathers (−40 µs).
#define LCOMP_NS(S) { \
    float wSV_ = fmaf(S##_f, bflo(S##_t.y), bfhi(S##_t.y)); \
    float wA_  = fmaf(S##_f, bflo(S##_t.z), bfhi(S##_t.z)); \
    float wB_  = fmaf(S##_f, bflo(S##_t.w), bfhi(S##_t.w)); \
    float ss_ = __uint_as_float((uint32)S##_s << 16); \
    float vx_ = bfhi(S##_v.x), vy_ = bflo(S##_v.x), vz_ = bfhi(S##_v.y); \
    float t_ = wSV_ * ss_; \
    av0 += t_ * S##_y0; av1 += t_ * S##_y1; av2 += t_ * S##_y2; \
    float cx_ = vy_ * S##_y2 - vz_ * S##_y1; \
    float cy_ = vz_ * S##_y0 - vx_ * S##_y2; \
    float cz_ = vx_ * S##_y1 - vy_ * S##_y0; \
    float wM_ = low ? wB_ : wA_; \
    b0 += wM_ * (low ? vx_ : cx_); \
    b1 += wM_ * (low ? vy_ : cy_); \
    b2 += wM_ * (low ? vz_ : cz_); \
  }

__global__ __launch_bounds__(256, 8) void k_agg_layer_ns(
    const float* __restrict__ cnoise, const float* __restrict__ nsw,
    const int* __restrict__ offsets, const int* __restrict__ order,
    const float* __restrict__ rec8,
    const uint32* __restrict__ TL, const ushort16* __restrict__ sh_bf,
    const uint32* __restrict__ vh_bf,
    float* __restrict__ a_v) {
  int lane = threadIdx.x & 63;
  int n = __builtin_amdgcn_readfirstlane(order[blockIdx.x * 4 + (threadIdx.x >> 6)]);
  int vc = lane & 31;
  bool low = lane < 32;
  const char* TLc = (const char*)TL;
  const char* SHc = (const char*)sh_bf;
  const char* VHc = (const char*)vh_bf;
  unsigned laneT = (unsigned)lane * 16u;
  unsigned laneS = (unsigned)lane * 2u;
  unsigned laneV = (unsigned)vc * 8u;
  float cn = cnoise[0];
  float scale_s = 1.f + cn * nsw[lane];
  float scale_v = 1.f + cn * nsw[64 + vc];
  float av0 = 0, av1 = 0, av2 = 0, b0 = 0, b1 = 0, b2 = 0;
  int beg = __builtin_amdgcn_readfirstlane(offsets[n]);
  int end = __builtin_amdgcn_readfirstlane(offsets[n + 1]);
  float S0_f, S0_y0, S0_y1, S0_y2; uint4 S0_t; ushort16 S0_s; uint2 S0_v;
  float S1_f, S1_y0, S1_y1, S1_y2; uint4 S1_t; ushort16 S1_s; uint2 S1_v;
  float S2_f, S2_y0, S2_y1, S2_y2; uint4 S2_t; ushort16 S2_s; uint2 S2_v;
  if (beg < end) {
    int last = end - 1;
    LISSUE(S0, beg);
    LISSUE(S1, (beg + 1 < end) ? beg + 1 : last);
    LISSUE(S2, (beg + 2 < end) ? beg + 2 : last);
    int i = beg;
    while (i + 3 <= end) {
      LCOMP_NS(S0); LISSUE(S0, (i + 3 < end) ? i + 3 : last);
      LCOMP_NS(S1); LISSUE(S1, (i + 4 < end) ? i + 4 : last);
      LCOMP_NS(S2); LISSUE(S2, (i + 5 < end) ? i + 5 : last);
      i += 3;
    }
    int rem = end - i;
    if (rem >= 1) LCOMP_NS(S0);
    if (rem >= 2) LCOMP_NS(S1);
  }
  float fs = scale_s * INV_NORM;
  float fv = scale_v * INV_NORM;
  float* avn = a_v + ((size_t)n << 9);
  *(float4*)(avn + (lane << 2)) = make_float4(av0 * fs, av1 * fs, av2 * fs, 0.f);
  if (low) {
    *(float4*)(avn + ((64 + vc) << 2)) = make_float4(b0 * fv, b1 * fv, b2 * fv, 0.f);
  } else {
    *(float4*)(avn + ((96 + vc) << 2)) = make_float4(b0 * fv, b1 * fv, b2 * fv, 0.f);
  }
}

// ---------------- merged init projections ----------------
// blocks 0..2047: s-path (36KB LDS); blocks 2048..4095: v-path (8KB of the same buffer)
__global__ __launch_bounds__(256, 4) void k_init(
    const float* __restrict__ a_s, const float* __restrict__ s_feat,
    const float* __restrict__ Ws0, const float* __restrict__ Wself0,
    const float* __restrict__ a_v, const float* __restrict__ Wv0,
    float* __restrict__ sh, ushort16* __restrict__ sh_bf,
    float* __restrict__ vh, uint32* __restrict__ vh_bf) {
  __shared__ __align__(16) char ldsbuf[36864];
  int tid = threadIdx.x;
  int bid = blockIdx.x;
  if (bid < 2048) {
    float* W1 = (float*)ldsbuf;              // 16KB
    float* W2 = (float*)(ldsbuf + 16384);    // 16KB
    float* La = (float*)(ldsbuf + 32768);    // 2KB
    float* Lf = (float*)(ldsbuf + 34816);    // 2KB
    for (int i = tid; i < 1024; i += 256) {
      ((float4*)W1)[i] = ((const float4*)Ws0)[i];
      ((float4*)W2)[i] = ((const float4*)Wself0)[i];
    }
    int base = bid * 8;
    for (int i = tid; i < 512; i += 256) {
      La[i] = a_s[(size_t)base * 64 + i];
      Lf[i] = s_feat[(size_t)base * 64 + i];
    }
    __syncthreads();
    int d = tid & 63, g = tid >> 6;
    int n0 = base + g * 2;
    const float* A0 = La + g * 128;
    const float* A1 = A0 + 64;
    const float* F0 = Lf + g * 128;
    const float* F1 = F0 + 64;
    float a0 = 0, a1 = 0;
#pragma unroll 8
    for (int c = 0; c < 64; ++c) {
      float w1 = W1[c * 64 + d], w2 = W2[c * 64 + d];
      a0 += A0[c] * w1 + F0[c] * w2;
      a1 += A1[c] * w1 + F1[c] * w2;
    }
    sh[(size_t)n0 * 64 + d] = a0;
    sh[(size_t)(n0 + 1) * 64 + d] = a1;
    sh_bf[(size_t)n0 * 64 + d] = f2bf(a0);
    sh_bf[(size_t)(n0 + 1) * 64 + d] = f2bf(a1);
  } else {
    float* W = (float*)ldsbuf;  // 8KB
    for (int i = tid; i < 512; i += 256) ((float4*)W)[i] = ((const float4*)Wv0)[i];
    __syncthreads();
    int d = tid & 31, g = tid >> 5;
    int n = (bid - 2048) * 8 + g;
    const float4* av = (const float4*)(a_v + ((size_t)n << 8));
    float x = 0, y = 0, z = 0;
#pragma unroll 4
    for (int c = 0; c < 64; ++c) {
      float4 a = av[c];
      float w = W[c * 32 + d];
      x += a.x * w; y += a.y * w; z += a.z * w;
    }
    *(float4*)(vh + ((size_t)n << 7) + (d << 2)) = make_float4(x, y, z, 0.f);
    *(uint2*)(vh_bf + ((size_t)n << 6) + (d << 1)) = make_uint2(packbf(x, y), packbf(z, 0.f));
  }
}

// ---------------- mix/self/skip: LDS-staged matvecs (+ bf16 mirrors) ----------------
__global__ __launch_bounds__(256, 4) void k_mix_s(
    const float* __restrict__ a_s, const float* __restrict__ sh_in,
    const float* __restrict__ Wmix_s, const float* __restrict__ Wself_s,
    const float* __restrict__ nsw, const float* __restrict__ skw,
    const float* __restrict__ skb, const float* __restrict__ cnoise,
    float* __restrict__ sh_out, ushort16* __restrict__ sh_bf_out) {
  __shared__ float Wm[96 * 64];   // 24KB
  __shared__ float Wsf[64 * 64];  // 16KB (scale folded in)
  __shared__ float La[8 * 96];    // 3KB
  int tid = threadIdx.x;
  float cn = cnoise[0];
  for (int i = tid; i < 96 * 16; i += 256) ((float4*)Wm)[i] = ((const float4*)Wmix_s)[i];
  for (int i = tid; i < 64 * 16; i += 256) {
    float4 wv = ((const float4*)Wself_s)[i];
    int c = i >> 4;
    float sc = 1.f + cn * nsw[c];
    wv.x *= sc; wv.y *= sc; wv.z *= sc; wv.w *= sc;
    ((float4*)Wsf)[i] = wv;
  }
  int base = blockIdx.x * 8;
  for (int i = tid; i < 8 * 96; i += 256) La[i] = a_s[(size_t)base * 96 + i];
  __syncthreads();
  int d = tid & 63, g = tid >> 6;
  int n0 = base + g * 2;
  const float* A0 = La + (g * 2) * 96;
  const float* A1 = A0 + 96;
  const float* s0p = sh_in + (size_t)n0 * 64;
  const float* s1p = s0p + 64;
  float acc0 = 0, acc1 = 0;
#pragma unroll 8
  for (int c = 0; c < 96; ++c) {
    float w = Wm[c * 64 + d];
    acc0 += A0[c] * w;
    acc1 += A1[c] * w;
  }
#pragma unroll 8
  for (int c = 0; c < 64; ++c) {
    float w = Wsf[c * 64 + d];
    acc0 += s0p[c] * w;
    acc1 += s1p[c] * w;
  }
  float g1 = sigmoidf_(skb[d] + cn * skw[d]);
  float g2 = sigmoidf_(skb[64 + d] + cn * skw[64 + d]);
  float o0 = g1 * s0p[d] + g2 * acc0;
  float o1 = g1 * s1p[d] + g2 * acc1;
  sh_out[(size_t)n0 * 64 + d] = o0;
  sh_out[(size_t)(n0 + 1) * 64 + d] = o1;
  sh_bf_out[(size_t)n0 * 64 + d] = f2bf(o0);
  sh_bf_out[(size_t)(n0 + 1) * 64 + d] = f2bf(o1);
}

// last==0: write vh_out + bf16 mirror. last==1: fused final projection to out, no stores.
__global__ __launch_bounds__(256, 4) void k_mix_v(
    const float* __restrict__ a_v, const float* __restrict__ vh_in,
    const float* __restrict__ Wmix_v, const float* __restrict__ Wself_v,
    const float* __restrict__ nsw, const float* __restrict__ skw,
    const float* __restrict__ skb, const float* __restrict__ cnoise,
    float* __restrict__ vh_out, uint32* __restrict__ vh_bf_out,
    const float* __restrict__ w_out, const float* __restrict__ gain,
    float* __restrict__ out, int last) {
  __shared__ float Wm[128 * 32];   // 16KB
  __shared__ float Wsf[32 * 32];   // 4KB (scale folded in)
  int tid = threadIdx.x;
  float cn = cnoise[0];
  for (int i = tid; i < 128 * 8; i += 256) ((float4*)Wm)[i] = ((const float4*)Wmix_v)[i];
  for (int i = tid; i < 32 * 8; i += 256) {
    float4 wv = ((const float4*)Wself_v)[i];
    int c = i >> 3;
    float sc = 1.f + cn * nsw[64 + c];
    wv.x *= sc; wv.y *= sc; wv.z *= sc; wv.w *= sc;
    ((float4*)Wsf)[i] = wv;
  }
  __syncthreads();
  int d = tid & 31, g = tid >> 5;
  int n = blockIdx.x * 8 + g;
  const float4* av = (const float4*)(a_v + ((size_t)n << 9));
  const float4* vr = (const float4*)(vh_in + ((size_t)n << 7));
  float x = 0, y = 0, z = 0;
#pragma unroll 4
  for (int c = 0; c < 128; ++c) {
    float4 a = av[c];
    float w = Wm[c * 32 + d];
    x += a.x * w; y += a.y * w; z += a.z * w;
  }
#pragma unroll 4
  for (int c = 0; c < 32; ++c) {
    float4 vv = vr[c];
    float w = Wsf[c * 32 + d];
    x += vv.x * w; y += vv.y * w; z += vv.z * w;
  }
  float g3 = sigmoidf_(skb[128 + d] + cn * skw[128 + d]);
  float g4 = sigmoidf_(skb[160 + d] + cn * skw[160 + d]);
  float4 vi = vr[d];
  float ox = g3 * vi.x + g4 * x;
  float oy = g3 * vi.y + g4 * y;
  float oz = g3 * vi.z + g4 * z;
  if (!last) {
    *(float4*)(vh_out + ((size_t)n << 7) + (d << 2)) = make_float4(ox, oy, oz, 0.f);
    *(uint2*)(vh_bf_out + ((size_t)n << 6) + (d << 1)) = make_uint2(packbf(ox, oy), packbf(oz, 0.f));
  } else {
    // fused final projection: out[n][i] = gain * sum_c w_out[c] * o_i[c]
    float wo = w_out[d];
    float px = wo * ox, py = wo * oy, pz = wo * oz;
#pragma unroll
    for (int m = 16; m >= 1; m >>= 1) {
      px += __shfl_xor(px, m, 32);
      py += __shfl_xor(py, m, 32);
      pz += __shfl_xor(pz, m, 32);
    }
    if (d == 0) {
      float gg = gain[0];
      out[n * 3 + 0] = px * gg;
      out[n * 3 + 1] = py * gg;
      out[n * 3 + 2] = pz * gg;
    }
  }
}

extern "C" void kernel_launch(void* const* d_in, const int* in_sizes, int n_in,
                              void* d_out, int out_size, void* d_ws, size_t ws_size,
                              hipStream_t stream) {
  (void)in_sizes; (void)n_in; (void)out_size; (void)ws_size;
  const float* pos     = (const float*)d_in[0];
  const float* cn      = (const float*)d_in[1];
  const int*   types   = (const int*)d_in[2];
  const int*   rad     = (const int*)d_in[3];
  const int*   bon     = (const int*)d_in[4];
  const float* atom_tab= (const float*)d_in[5];
  const float* bond_tab= (const float*)d_in[6];
  const float* ns0_w   = (const float*)d_in[7];
  const float* We0     = (const float*)d_in[8];
  const float* We1     = (const float*)d_in[9];
  const float* Wself0  = (const float*)d_in[10];
  const float* Ws0     = (const float*)d_in[11];
  const float* Wv0     = (const float*)d_in[12];
  const float* ns_w    = (const float*)d_in[13];
  const float* We_ss   = (const float*)d_in[14];
  const float* We_vs   = (const float*)d_in[15];
  const float* We_sv   = (const float*)d_in[16];
  const float* We_vv   = (const float*)d_in[17];
  const float* We_vx   = (const float*)d_in[18];
  const float* Wmix_s  = (const float*)d_in[19];
  const float* Wmix_v  = (const float*)d_in[20];
  const float* Wself_s = (const float*)d_in[21];
  const float* Wself_v = (const float*)d_in[22];
  const float* skip_w  = (const float*)d_in[23];
  const float* skip_b  = (const float*)d_in[24];
  const float* w_out   = (const float*)d_in[25];
  const float* gain    = (const float*)d_in[26];

  char* ws = (char*)d_ws;
  size_t o = 0;
  auto alloc = [&](size_t bytes) -> void* {
    void* p = ws + o;
    o += (bytes + 255) & ~(size_t)255;
    return p;
  };
  float* s_feat  = (float*)alloc((size_t)NA * 64 * 4);
  ushort16* s_bf = (ushort16*)alloc((size_t)NA * 64 * 2);
  float* a_s     = (float*)alloc((size_t)NA * 96 * 4);
  float* a_v     = (float*)alloc((size_t)NA * 512 * 4);  // [n][128][4]; agg0 uses [n][64][4]
  float* sh0     = (float*)alloc((size_t)NA * 64 * 4);
  float* sh1     = (float*)alloc((size_t)NA * 64 * 4);
  ushort16* shbf0= (ushort16*)alloc((size_t)NA * 64 * 2);
  ushort16* shbf1= (ushort16*)alloc((size_t)NA * 64 * 2);
  float* vh0     = (float*)alloc((size_t)NA * 128 * 4);  // [n][32][4]
  float* vh1     = (float*)alloc((size_t)NA * 128 * 4);
  uint32* vhbf0  = (uint32*)alloc((size_t)NA * 64 * 4);  // [n][32][2] uints
  uint32* vhbf1  = (uint32*)alloc((size_t)NA * 64 * 4);
  int* count     = (int*)alloc((size_t)NA * 4);
  int* offsets   = (int*)alloc((size_t)(NA + 1) * 4);
  int* cursor    = (int*)alloc((size_t)NA * 4);
  int* order     = (int*)alloc((size_t)NA * 4);
  float* rec8    = (float*)alloc((size_t)ET * 32);
  uint32* T0     = (uint32*)alloc((size_t)T0U * 4);
  uint32* TL     = (uint32*)alloc((size_t)2 * TLU * 4);
  float* shb[2]  = {sh0, sh1};
  ushort16* shbf[2] = {shbf0, shbf1};
  float* vhb[2]  = {vh0, vh1};
  uint32* vhbf[2]= {vhbf0, vhbf1};

  // CSR build + LPT order + tables
  hipMemsetAsync(count, 0, (size_t)NA * 4, stream);
  k_hist<<<ET / 256, 256, 0, stream>>>(rad, bon, count);
  k_scan_all<<<1, 1024, 0, stream>>>(count, offsets, cursor, order);
  k_fill_pre<<<ET / 256, 256, 0, stream>>>(rad, bon, cursor, pos, rec8);
  k_embed_build<<<4096 + 768, 256, 0, stream>>>(atom_tab, types, ns0_w, cn, s_feat, s_bf,
                                                We0, We1, We_ss, We_vs, We_sv, We_vv, We_vx,
                                                bond_tab, T0, TL);

  k_agg0<<<NA / 4, 256, 0, stream>>>(offsets, order, rec8, T0, s_bf, a_s, a_v);
  k_init<<<4096, 256, 0, stream>>>(a_s, s_feat, Ws0, Wself0, a_v, Wv0,
                                   shb[0], shbf[0], vhb[0], vhbf[0]);

  // layer 0 (full)
  k_agg_layer<<<NA / 4, 256, 0, stream>>>(
      cn, ns_w, offsets, order, rec8, TL, shbf[0], vhbf[0], a_s, a_v);
  k_mix_s<<<NA / 8, 256, 0, stream>>>(
      a_s, shb[0], Wmix_s, Wself_s, ns_w, skip_w, skip_b, cn, shb[1], shbf[1]);
  k_mix_v<<<NA / 8, 256, 0, stream>>>(
      a_v, vhb[0], Wmix_v, Wself_v, ns_w, skip_w, skip_b, cn,
      vhb[1], vhbf[1], w_out, gain, (float*)d_out, 0);

  // layer 1 (s-output dead: NS agg, no mix_s, fused final projection)
  k_agg_layer_ns<<<NA / 4, 256, 0, stream>>>(
      cn, ns_w + 96, offsets, order, rec8, TL + (size_t)TLU, shbf[1], vhbf[1], a_v);
  k_mix_v<<<NA / 8, 256, 0, stream>>>(
      a_v, vhb[1], Wmix_v + 128 * 32, Wself_v + 32 * 32,
      ns_w + 96, skip_w + 192, skip_b + 192, cn,
      nullptr, nullptr, w_out, gain, (float*)d_out, 1);
}